// Round 10
// baseline (18.777 us; speedup 1.0000x reference)
//
#include <hip/hip_runtime.h>

typedef short short8 __attribute__((ext_vector_type(8)));
typedef float f32x4 __attribute__((ext_vector_type(4)));

static __device__ __forceinline__ unsigned short f2bf(float f) {
    unsigned u = __builtin_bit_cast(unsigned, f);
    u += 0x7FFFu + ((u >> 16) & 1u);   // RNE
    return (unsigned short)(u >> 16);
}

// Single kernel, single launch. Block = (b, 32-pixel tile, 64-col tile),
// 4 waves; grid 1024 = 4 blocks/CU = 4 waves/SIMD (R9 was 2 -> latency-bound).
// All prep recomputed per block (verified R9 structure, tile halved):
//  - A (patches) staged once -> bf16 swizzled LDS
//  - B (Wp) and We read as direct global gathers (L2-resident)
//  - inj slice via E-staging + MFMA, bounced through wave-private LDS,
//    rc folded into the mask MFMA fragment.
// ONE __syncthreads; no inter-block dependency; no workspace.
__global__ __launch_bounds__(256)
void fused_all(const float* __restrict__ patches,
               const float* __restrict__ embs,
               const int* __restrict__ locations,
               const float* __restrict__ Wp,
               const float* __restrict__ We,
               float* __restrict__ out) {
    __shared__ __align__(16) unsigned short Ash[32 * 256];    // 16 KB, swizzled
    __shared__ __align__(16) unsigned short Ebf[16 * 256];    // 8 KB, swizzled
    __shared__ __align__(16) unsigned short injW[4 * 16 * 32];// 4 KB, [wave][col][n]
    __shared__ unsigned maskL[32];
    __shared__ float rcL[32];

    const int bid = blockIdx.x, t = threadIdx.x;
    const int b = bid >> 7, pt = (bid >> 2) & 31, ct = bid & 3;
    const int p0 = pt * 32, c0 = ct * 64;
    const int wv = t >> 6, lane = t & 63, lhi = lane >> 4, llo = lane & 15;
    const int oc = c0 + wv * 16 + llo;   // output column this lane owns

    // ---- A staging: patches[b, p0..p0+32, :] -> bf16 LDS, XOR-swizzled rows ----
    const float* pbase = patches + (size_t)(b * 1024 + p0) * 256;
    #pragma unroll
    for (int it = 0; it < 8; ++it) {
        int u = t + it * 256;
        int row = u >> 6, c4 = u & 63;
        float4 f = *reinterpret_cast<const float4*>(pbase + row * 256 + c4 * 4);
        ushort4 o;
        o.x = f2bf(f.x); o.y = f2bf(f.y); o.z = f2bf(f.z); o.w = f2bf(f.w);
        int byte = row * 512 + ((c4 * 8) ^ ((row & 7) << 4));
        *reinterpret_cast<ushort4*>(reinterpret_cast<char*>(Ash) + byte) = o;
    }

    // ---- E staging: embs rows 0..14 (bf16, swizzled) + f32-accurate mean row 15 ----
    if (t < 128) {
        const int c0e = t * 2;
        float s0 = 0.f, s1 = 0.f;
        #pragma unroll
        for (int r = 0; r < 15; ++r) {
            float2 v = *reinterpret_cast<const float2*>(embs + (size_t)(b * 15 + r) * 256 + c0e);
            s0 += v.x; s1 += v.y;
            unsigned pk = (unsigned)f2bf(v.x) | ((unsigned)f2bf(v.y) << 16);
            *reinterpret_cast<unsigned*>(reinterpret_cast<char*>(Ebf)
                + r * 512 + ((c0e * 2) ^ ((r & 7) << 4))) = pk;
        }
        unsigned pk = (unsigned)f2bf(s0 * (1.0f / 15.0f))
                    | ((unsigned)f2bf(s1 * (1.0f / 15.0f)) << 16);
        *reinterpret_cast<unsigned*>(reinterpret_cast<char*>(Ebf)
            + 15 * 512 + ((c0e * 2) ^ (7 << 4))) = pk;
    }

    // ---- masks + 1/cnt for the 32 pixels ----
    if (t < 32) {
        int p = p0 + t;
        int h = p >> 5, w = p & 31;
        const int* loc = locations + b * 60;
        unsigned m = 1u << 15;  // full-image box always contains
        #pragma unroll
        for (int nb = 0; nb < 15; ++nb) {
            int y0 = loc[nb * 4 + 0] & ~1;
            int x0 = loc[nb * 4 + 1] & ~1;
            int y1 = (loc[nb * 4 + 2] & ~1) + 2;
            int x1 = (loc[nb * 4 + 3] & ~1) + 2;
            if (h >= y0 && h < y1 && w >= x0 && w < x1) m |= 1u << nb;
        }
        maskL[t] = m;
        rcL[t] = 1.0f / (float)__popc(m);
    }
    __syncthreads();   // the ONLY block barrier

    // ---- inj slice: (E_ext @ We)[:, oc] via MFMA (wave-private) ----
    f32x4 accI = (f32x4){0.f, 0.f, 0.f, 0.f};
    #pragma unroll
    for (int ks = 0; ks < 8; ++ks) {
        const short8 afr = *reinterpret_cast<const short8*>(
            reinterpret_cast<const char*>(Ebf)
            + llo * 512 + ((ks * 64 + lhi * 16) ^ ((llo & 7) << 4)));
        short8 bfr;
        #pragma unroll
        for (int r = 0; r < 8; ++r)
            bfr[r] = (short)f2bf(We[(size_t)(ks * 32 + lhi * 8 + r) * 256 + oc]);
        accI = __builtin_amdgcn_mfma_f32_16x16x32_bf16(afr, bfr, accI, 0, 0, 0);
    }
    // bounce to [col][n] bf16 (+ zero-pad n=16..31) -> jf fragment
    {
        ushort4 o4;
        o4.x = f2bf(accI[0]); o4.y = f2bf(accI[1]);
        o4.z = f2bf(accI[2]); o4.w = f2bf(accI[3]);
        unsigned short* dst = injW + wv * 512 + llo * 32;
        *reinterpret_cast<ushort4*>(dst + lhi * 4) = o4;
        ushort4 z = {0, 0, 0, 0};
        *reinterpret_cast<ushort4*>(dst + 16 + lhi * 4) = z;
    }
    asm volatile("s_waitcnt lgkmcnt(0)" ::: "memory");
    __builtin_amdgcn_sched_barrier(0);
    const short8 jf = *reinterpret_cast<const short8*>(injW + wv * 512 + llo * 32 + lhi * 8);

    // ---- main GEMM: 2 pixel-groups x 8 k-steps; B gathered from Wp (L2) ----
    f32x4 acc[2];
    #pragma unroll
    for (int mt = 0; mt < 2; ++mt) acc[mt] = (f32x4){0.f, 0.f, 0.f, 0.f};
    #pragma unroll
    for (int ks = 0; ks < 8; ++ks) {
        short8 bfr;
        #pragma unroll
        for (int r = 0; r < 8; ++r)
            bfr[r] = (short)f2bf(Wp[(size_t)(ks * 32 + lhi * 8 + r) * 256 + oc]);
        #pragma unroll
        for (int mt = 0; mt < 2; ++mt) {
            int row = mt * 16 + llo;
            const short8 af = *reinterpret_cast<const short8*>(
                reinterpret_cast<const char*>(Ash)
                + row * 512 + (((ks * 32 + lhi * 8) * 2) ^ ((row & 7) << 4)));
            acc[mt] = __builtin_amdgcn_mfma_f32_16x16x32_bf16(af, bfr, acc[mt], 0, 0, 0);
        }
    }

    // ---- epilogue: rc-folded mask MFMA per pixel-group, then store ----
    #pragma unroll
    for (int mt = 0; mt < 2; ++mt) {
        unsigned m = maskL[mt * 16 + llo];
        unsigned short rcb = f2bf(rcL[mt * 16 + llo]);
        short8 mfrag;
        #pragma unroll
        for (int r = 0; r < 8; ++r) {
            int k = lhi * 8 + r;
            mfrag[r] = (k < 16 && ((m >> k) & 1u)) ? (short)rcb : (short)0;
        }
        f32x4 accE = __builtin_amdgcn_mfma_f32_16x16x32_bf16(
            mfrag, jf, (f32x4){0.f, 0.f, 0.f, 0.f}, 0, 0, 0);
        float* ob = out + (size_t)(b * 1024 + p0 + mt * 16) * 256;
        #pragma unroll
        for (int j = 0; j < 4; ++j)
            ob[(lhi * 4 + j) * 256 + oc] = acc[mt][j] + accE[j];
    }
}

extern "C" void kernel_launch(void* const* d_in, const int* in_sizes, int n_in,
                              void* d_out, int out_size, void* d_ws, size_t ws_size,
                              hipStream_t stream) {
    const float* patches = (const float*)d_in[0];
    const float* embs    = (const float*)d_in[1];
    const int*   locs    = (const int*)d_in[2];
    const float* Wp      = (const float*)d_in[3];
    const float* We      = (const float*)d_in[4];
    float* out = (float*)d_out;

    fused_all<<<1024, 256, 0, stream>>>(patches, embs, locs, Wp, We, out);
}

// Round 12
// 16.296 us; speedup vs baseline: 1.1522x; 1.1522x over previous
//
#include <hip/hip_runtime.h>
#include <hip/hip_bf16.h>

typedef short short8 __attribute__((ext_vector_type(8)));
typedef float f32x4 __attribute__((ext_vector_type(4)));

// RNE f32->bf16 via hardware v_cvt_pk_bf16_f32 (compiler-scheduled; the HIP
// intrinsic, NOT inline asm — m240: hand-written asm cvt_pk blocks scheduling).
// __hip_bfloat162 is not trivially copyable -> extract bits via memcpy (no-op).
static __device__ __forceinline__ ushort2 pk2(float a, float b) {
    __hip_bfloat162 h = __float22bfloat162_rn(make_float2(a, b));
    ushort2 r;
    __builtin_memcpy(&r, &h, 4);
    return r;
}
static __device__ __forceinline__ unsigned short bf1(float a) {
    __hip_bfloat16 h = __float2bfloat16(a);
    unsigned short r;
    __builtin_memcpy(&r, &h, 2);
    return r;
}

// Single kernel, single launch (R9-verified structure, 17.1us).
// Block = (b, 64-pixel tile, 64-col tile), 4 waves; wave = 16 cols x 64 px.
//  - A (patches) staged once -> bf16 swizzled LDS
//  - B (Wp) and We read as direct global gathers (L2-resident)
//  - inj slice via E-staging + MFMA, bounced through wave-private LDS,
//    rc folded into the mask MFMA fragment.
// ONE __syncthreads; no inter-block dependency; no workspace.
__global__ __launch_bounds__(256)
void fused_all(const float* __restrict__ patches,
               const float* __restrict__ embs,
               const int* __restrict__ locations,
               const float* __restrict__ Wp,
               const float* __restrict__ We,
               float* __restrict__ out) {
    __shared__ __align__(16) unsigned short Ash[64 * 256];    // 32 KB, swizzled
    __shared__ __align__(16) unsigned short Ebf[16 * 256];    // 8 KB, swizzled
    __shared__ __align__(16) unsigned short injW[4 * 16 * 32];// 4 KB, [wave][col][n]
    __shared__ unsigned maskL[64];
    __shared__ float rcL[64];

    const int bid = blockIdx.x, t = threadIdx.x;
    const int b = bid >> 6, pt = (bid >> 2) & 15, ct = bid & 3;
    const int p0 = pt * 64, c0 = ct * 64;
    const int wv = t >> 6, lane = t & 63, lhi = lane >> 4, llo = lane & 15;
    const int oc = c0 + wv * 16 + llo;   // output column this lane owns

    // ---- A staging: patches[b, p0..p0+64, :] -> bf16 LDS, XOR-swizzled rows ----
    const float* pbase = patches + (size_t)(b * 1024 + p0) * 256;
    #pragma unroll
    for (int it = 0; it < 16; ++it) {
        int u = t + it * 256;
        int row = u >> 6, c4 = u & 63;
        float4 f = *reinterpret_cast<const float4*>(pbase + row * 256 + c4 * 4);
        ushort2 lo = pk2(f.x, f.y), hi = pk2(f.z, f.w);
        ushort4 o = {lo.x, lo.y, hi.x, hi.y};
        int byte = row * 512 + ((c4 * 8) ^ ((row & 7) << 4));
        *reinterpret_cast<ushort4*>(reinterpret_cast<char*>(Ash) + byte) = o;
    }

    // ---- E staging: embs rows 0..14 (bf16, swizzled) + f32-accurate mean row 15 ----
    if (t < 128) {
        const int c0e = t * 2;
        float s0 = 0.f, s1 = 0.f;
        #pragma unroll
        for (int r = 0; r < 15; ++r) {
            float2 v = *reinterpret_cast<const float2*>(embs + (size_t)(b * 15 + r) * 256 + c0e);
            s0 += v.x; s1 += v.y;
            ushort2 p2 = pk2(v.x, v.y);
            unsigned pk = (unsigned)p2.x | ((unsigned)p2.y << 16);
            *reinterpret_cast<unsigned*>(reinterpret_cast<char*>(Ebf)
                + r * 512 + ((c0e * 2) ^ ((r & 7) << 4))) = pk;
        }
        ushort2 p2 = pk2(s0 * (1.0f / 15.0f), s1 * (1.0f / 15.0f));
        unsigned pk = (unsigned)p2.x | ((unsigned)p2.y << 16);
        *reinterpret_cast<unsigned*>(reinterpret_cast<char*>(Ebf)
            + 15 * 512 + ((c0e * 2) ^ (7 << 4))) = pk;
    }

    // ---- masks + 1/cnt for the 64 pixels ----
    if (t < 64) {
        int p = p0 + t;
        int h = p >> 5, w = p & 31;
        const int* loc = locations + b * 60;
        unsigned m = 1u << 15;  // full-image box always contains
        #pragma unroll
        for (int nb = 0; nb < 15; ++nb) {
            int y0 = loc[nb * 4 + 0] & ~1;
            int x0 = loc[nb * 4 + 1] & ~1;
            int y1 = (loc[nb * 4 + 2] & ~1) + 2;
            int x1 = (loc[nb * 4 + 3] & ~1) + 2;
            if (h >= y0 && h < y1 && w >= x0 && w < x1) m |= 1u << nb;
        }
        maskL[t] = m;
        rcL[t] = 1.0f / (float)__popc(m);
    }
    __syncthreads();   // the ONLY block barrier

    // ---- inj slice: (E_ext @ We)[:, oc] via MFMA (wave-private) ----
    f32x4 accI = (f32x4){0.f, 0.f, 0.f, 0.f};
    #pragma unroll
    for (int ks = 0; ks < 8; ++ks) {
        const short8 afr = *reinterpret_cast<const short8*>(
            reinterpret_cast<const char*>(Ebf)
            + llo * 512 + ((ks * 64 + lhi * 16) ^ ((llo & 7) << 4)));
        short8 bfr;
        #pragma unroll
        for (int rr = 0; rr < 4; ++rr) {
            float w0 = We[(size_t)(ks * 32 + lhi * 8 + 2 * rr + 0) * 256 + oc];
            float w1 = We[(size_t)(ks * 32 + lhi * 8 + 2 * rr + 1) * 256 + oc];
            ushort2 p2 = pk2(w0, w1);
            bfr[2 * rr + 0] = (short)p2.x;
            bfr[2 * rr + 1] = (short)p2.y;
        }
        accI = __builtin_amdgcn_mfma_f32_16x16x32_bf16(afr, bfr, accI, 0, 0, 0);
    }
    // bounce to [col][n] bf16 (+ zero-pad n=16..31) -> jf fragment
    {
        ushort2 lo = pk2(accI[0], accI[1]), hi = pk2(accI[2], accI[3]);
        ushort4 o4 = {lo.x, lo.y, hi.x, hi.y};
        unsigned short* dst = injW + wv * 512 + llo * 32;
        *reinterpret_cast<ushort4*>(dst + lhi * 4) = o4;
        ushort4 z = {0, 0, 0, 0};
        *reinterpret_cast<ushort4*>(dst + 16 + lhi * 4) = z;
    }
    asm volatile("s_waitcnt lgkmcnt(0)" ::: "memory");
    __builtin_amdgcn_sched_barrier(0);
    const short8 jf = *reinterpret_cast<const short8*>(injW + wv * 512 + llo * 32 + lhi * 8);

    // ---- main GEMM: 4 pixel-groups x 8 k-steps; B gathered from Wp (L2) ----
    f32x4 acc[4];
    #pragma unroll
    for (int mt = 0; mt < 4; ++mt) acc[mt] = (f32x4){0.f, 0.f, 0.f, 0.f};
    #pragma unroll
    for (int ks = 0; ks < 8; ++ks) {
        short8 bfr;
        #pragma unroll
        for (int rr = 0; rr < 4; ++rr) {
            float w0 = Wp[(size_t)(ks * 32 + lhi * 8 + 2 * rr + 0) * 256 + oc];
            float w1 = Wp[(size_t)(ks * 32 + lhi * 8 + 2 * rr + 1) * 256 + oc];
            ushort2 p2 = pk2(w0, w1);
            bfr[2 * rr + 0] = (short)p2.x;
            bfr[2 * rr + 1] = (short)p2.y;
        }
        #pragma unroll
        for (int mt = 0; mt < 4; ++mt) {
            int row = mt * 16 + llo;
            const short8 af = *reinterpret_cast<const short8*>(
                reinterpret_cast<const char*>(Ash)
                + row * 512 + (((ks * 32 + lhi * 8) * 2) ^ ((row & 7) << 4)));
            acc[mt] = __builtin_amdgcn_mfma_f32_16x16x32_bf16(af, bfr, acc[mt], 0, 0, 0);
        }
    }

    // ---- epilogue: rc-folded mask MFMA per pixel-group, then store ----
    #pragma unroll
    for (int mt = 0; mt < 4; ++mt) {
        unsigned m = maskL[mt * 16 + llo];
        unsigned short rcb = bf1(rcL[mt * 16 + llo]);
        short8 mfrag;
        #pragma unroll
        for (int r = 0; r < 8; ++r) {
            int k = lhi * 8 + r;
            mfrag[r] = (k < 16 && ((m >> k) & 1u)) ? (short)rcb : (short)0;
        }
        f32x4 accE = __builtin_amdgcn_mfma_f32_16x16x32_bf16(
            mfrag, jf, (f32x4){0.f, 0.f, 0.f, 0.f}, 0, 0, 0);
        float* ob = out + (size_t)(b * 1024 + p0 + mt * 16) * 256;
        #pragma unroll
        for (int j = 0; j < 4; ++j)
            ob[(lhi * 4 + j) * 256 + oc] = acc[mt][j] + accE[j];
    }
}

extern "C" void kernel_launch(void* const* d_in, const int* in_sizes, int n_in,
                              void* d_out, int out_size, void* d_ws, size_t ws_size,
                              hipStream_t stream) {
    const float* patches = (const float*)d_in[0];
    const float* embs    = (const float*)d_in[1];
    const int*   locs    = (const int*)d_in[2];
    const float* Wp      = (const float*)d_in[3];
    const float* We      = (const float*)d_in[4];
    float* out = (float*)d_out;

    fused_all<<<512, 256, 0, stream>>>(patches, embs, locs, Wp, We, out);
}